// Round 6
// baseline (27002.618 us; speedup 1.0000x reference)
//
#include <hip/hip_runtime.h>
#include <hip/hip_bf16.h>
#include <math.h>

// Problem constants (fixed by the reference)
#define T_STEPS 4096
#define N_IN    8192
#define N_OUT   2048

// ---------------------------------------------------------------------------
// Kernel 1: u_proj = x @ Win   (f32 vector GEMM, 128x128 tile, BK=16)
//   Writes into d_out; the recurrence consumes/overwrites it in place.
// ---------------------------------------------------------------------------
#define GM_BK 16

__global__ __launch_bounds__(256) void gemm_xwin(const float* __restrict__ X,
                                                 const float* __restrict__ Win,
                                                 float* __restrict__ U) {
    const int K = N_IN, N = N_OUT;
    __shared__ float As[GM_BK][128 + 4];
    __shared__ float Bs[GM_BK][128 + 4];

    const int tid = threadIdx.x;
    const int bm = blockIdx.x;
    const int bn = blockIdx.y;
    const int tx = tid & 15;
    const int ty = tid >> 4;

    float acc[8][8];
#pragma unroll
    for (int i = 0; i < 8; i++)
#pragma unroll
        for (int j = 0; j < 8; j++) acc[i][j] = 0.f;

    const float* Xb = X + (size_t)(bm * 128) * K;
    const float* Wb = Win + bn * 128;

    for (int kt = 0; kt < K; kt += GM_BK) {
#pragma unroll
        for (int q = 0; q < 2; q++) {
            const int r  = (tid >> 2) + q * 64;
            const int c4 = (tid & 3) * 4;
            const float4 a4 = *reinterpret_cast<const float4*>(&Xb[(size_t)r * K + kt + c4]);
            As[c4 + 0][r] = a4.x;
            As[c4 + 1][r] = a4.y;
            As[c4 + 2][r] = a4.z;
            As[c4 + 3][r] = a4.w;
        }
#pragma unroll
        for (int q = 0; q < 2; q++) {
            const int r  = (tid >> 5) + q * 8;
            const int c4 = (tid & 31) * 4;
            *reinterpret_cast<float4*>(&Bs[r][c4]) =
                *reinterpret_cast<const float4*>(&Wb[(size_t)(kt + r) * N + c4]);
        }
        __syncthreads();

#pragma unroll
        for (int k = 0; k < GM_BK; k++) {
            float a[8], b[8];
#pragma unroll
            for (int i = 0; i < 4; i++) {
                a[i]     = As[k][ty * 4 + i];
                a[4 + i] = As[k][64 + ty * 4 + i];
            }
#pragma unroll
            for (int j = 0; j < 4; j++) {
                b[j]     = Bs[k][tx * 4 + j];
                b[4 + j] = Bs[k][64 + tx * 4 + j];
            }
#pragma unroll
            for (int i = 0; i < 8; i++)
#pragma unroll
                for (int j = 0; j < 8; j++)
                    acc[i][j] = fmaf(a[i], b[j], acc[i][j]);
        }
        __syncthreads();
    }

#pragma unroll
    for (int i = 0; i < 8; i++) {
        const int mr = bm * 128 + ((i < 4) ? (ty * 4 + i) : (64 + ty * 4 + (i - 4)));
        float* Crow = U + (size_t)mr * N + bn * 128;
        float4 v0 = make_float4(acc[i][0], acc[i][1], acc[i][2], acc[i][3]);
        float4 v1 = make_float4(acc[i][4], acc[i][5], acc[i][6], acc[i][7]);
        *reinterpret_cast<float4*>(&Crow[tx * 4])      = v0;
        *reinterpret_cast<float4*>(&Crow[64 + tx * 4]) = v1;
    }
}

// ---------------------------------------------------------------------------
// Kernel 2: sequential ESN recurrence, v6 = fine-grained DATAFLOW.
//   No barrier, no LDS staging in the hot loop. Each 16-lane group owns one
//   column and gathers exactly its ~205 tagged inputs straight from the
//   global slot array (tag = step). A group proceeds as soon as ITS inputs
//   arrive — block skew no longer compounds through a global max.
//   4-deep buffer rotation (t&3): a wave storing tag t+1 has transitively
//   forced every wave past step t-2 (2-hop sparsity coverage is total at
//   this density), so the overwritten tag-(t-3) content has no readers.
//   Determinism: arrivals land in fixed register slots; accumulation is a
//   fixed-order unrolled chain.
// ---------------------------------------------------------------------------
#define RB   128   // blocks (<= 256 CUs: co-resident)
#define CPB  16    // columns per block
#define GRP  16    // lanes per column
#define CAP  288   // nnz capacity per column (mean 204.8, sigma 13.6)
#define KMAX (CAP / GRP)   // 18 register entries per lane

__device__ __forceinline__ float fast_tanh(float x) {
    const float ax = fabsf(x);
    const float e  = __expf(2.0f * ax);               // inf for big ax
    const float r  = __builtin_amdgcn_rcpf(e + 1.0f); // rcp(inf)=0 -> tanh=1
    const float t  = 1.0f - 2.0f * r;
    return copysignf(t, x);
}

__global__ __launch_bounds__(256, 1) void esn_recur(const float* __restrict__ W,
                                                    float* __restrict__ UO,
                                                    unsigned long long* vslots) {
    __shared__ unsigned long long ent[CPB][CAP];  // setup scratch only
    __shared__ int cnts[CPB];

    const int tid = threadIdx.x;
    const int b   = blockIdx.x;
    const int c   = tid >> 4;              // column group 0..15
    const int l   = tid & 15;              // lane within group
    const int j   = b * CPB + c;           // global output column

    // ---------- build sparse column into LDS scratch (one-time) ----------
    int cnt = 0;
    for (int k = 0; k < N_OUT / GRP; k++) {
        const float w = W[(size_t)(l + GRP * k) * N_OUT + j];
        cnt += (w != 0.0f) ? 1 : 0;
    }
    int inc = cnt;
#pragma unroll
    for (int d = 1; d < GRP; d <<= 1) {
        int n = __shfl_up(inc, d, 64);
        if (l >= d) inc += n;
    }
    int pos = inc - cnt;
    if (l == GRP - 1) cnts[c] = inc;
    for (int k = 0; k < N_OUT / GRP; k++) {
        const int i = l + GRP * k;
        const float w = W[(size_t)i * N_OUT + j];
        if (w != 0.0f) {
            if (pos < CAP)
                ent[c][pos] = ((unsigned long long)(unsigned)i << 32) | __float_as_uint(w);
            pos++;
        }
    }
    __syncthreads();
    const int ccnt = min(cnts[c], CAP);

    // ---------- per-lane entries -> registers ----------
    float wreg[KMAX];
    int   idx[KMAX];
    unsigned valid = 0;
#pragma unroll
    for (int k = 0; k < KMAX; k++) {
        const int p = l + k * GRP;
        if (p < ccnt) {
            const unsigned long long e = ent[c][p];
            wreg[k] = __uint_as_float((unsigned)e);
            idx[k]  = (int)(e >> 32);
            valid |= (1u << k);
        } else {
            wreg[k] = 0.f;
            idx[k]  = 0;
        }
    }

    // ---------- sequential scan over T (pure dataflow, no barriers) ----------
#pragma unroll 1
    for (int t = 0; t < T_STEPS; t++) {
        const unsigned long long* vin = vslots + (size_t)(t & 3) * N_OUT;

        float u = 0.f;
        if (l == 0) u = UO[(size_t)t * N_OUT + j];

        unsigned long long uq[KMAX];
        float val[KMAX];
        unsigned pend = valid;
        bool pend_s = (l == 0);            // leak-term slot v_t[j] on lane 0
        unsigned long long uqs = 0;
        float vold = 0.f;
#pragma unroll
        for (int k = 0; k < KMAX; k++) val[k] = 0.f;

        // initial issue: all needed slots in flight at once
#pragma unroll
        for (int k = 0; k < KMAX; k++)
            if (pend & (1u << k))
                uq[k] = __hip_atomic_load(&vin[idx[k]], __ATOMIC_RELAXED,
                                          __HIP_MEMORY_SCOPE_AGENT);
        if (pend_s)
            uqs = __hip_atomic_load(&vin[j], __ATOMIC_RELAXED,
                                    __HIP_MEMORY_SCOPE_AGENT);

#pragma unroll 1
        while (true) {
#pragma unroll
            for (int k = 0; k < KMAX; k++) {
                if (pend & (1u << k)) {
                    if ((unsigned)(uq[k] >> 32) == (unsigned)t) {
                        val[k] = __uint_as_float((unsigned)uq[k]);
                        pend &= ~(1u << k);
                    }
                }
            }
            if (pend_s && (unsigned)(uqs >> 32) == (unsigned)t) {
                vold = __uint_as_float((unsigned)uqs);
                pend_s = false;
            }
            if (!__any(pend != 0 || pend_s)) break;
            // re-issue only pending slots
#pragma unroll
            for (int k = 0; k < KMAX; k++)
                if (pend & (1u << k))
                    uq[k] = __hip_atomic_load(&vin[idx[k]], __ATOMIC_RELAXED,
                                              __HIP_MEMORY_SCOPE_AGENT);
            if (pend_s)
                uqs = __hip_atomic_load(&vin[j], __ATOMIC_RELAXED,
                                        __HIP_MEMORY_SCOPE_AGENT);
        }

        // fixed-order FMA (deterministic), 3 accumulators of 6
        float y0 = 0.f, y1 = 0.f, y2 = 0.f;
#pragma unroll
        for (int k = 0; k < KMAX; k += 3) {
            y0 = fmaf(wreg[k + 0], val[k + 0], y0);
            y1 = fmaf(wreg[k + 1], val[k + 1], y1);
            y2 = fmaf(wreg[k + 2], val[k + 2], y2);
        }
        float y = (y0 + y1) + y2;
#pragma unroll
        for (int d = GRP / 2; d >= 1; d >>= 1) y += __shfl_xor(y, d, 64);

        if (l == 0) {
            const float vnew = 0.5f * vold + 0.5f * fast_tanh(y + u);
            // slot store FIRST (inter-block critical path), then the output
            const unsigned long long slot =
                ((unsigned long long)(unsigned)(t + 1) << 32) | __float_as_uint(vnew);
            __hip_atomic_store(&vslots[(size_t)((t + 1) & 3) * N_OUT + j], slot,
                               __ATOMIC_RELAXED, __HIP_MEMORY_SCOPE_AGENT);
            UO[(size_t)t * N_OUT + j] = vnew;
        }
    }
}

// ---------------------------------------------------------------------------
extern "C" void kernel_launch(void* const* d_in, const int* in_sizes, int n_in,
                              void* d_out, int out_size, void* d_ws, size_t ws_size,
                              hipStream_t stream) {
    const float* x   = (const float*)d_in[0];   // [4096, 8192]
    const float* W   = (const float*)d_in[1];   // [2048, 2048]
    const float* Win = (const float*)d_in[2];   // [8192, 2048]
    float* out = (float*)d_out;                 // [4096, 2048]

    unsigned long long* vslots = (unsigned long long*)d_ws;  // 4 x N_OUT x 8B

    // zero ALL four buffers every launch: buffer0 {tag=0,v=0} = zero state;
    // stale tags from a previous replay would collide with expected values.
    hipMemsetAsync(d_ws, 0, 4 * N_OUT * sizeof(unsigned long long), stream);

    dim3 ggrid(T_STEPS / 128, N_OUT / 128);
    gemm_xwin<<<ggrid, 256, 0, stream>>>(x, Win, out);

    esn_recur<<<RB, 256, 0, stream>>>(W, out, vslots);
}